// Round 8
// baseline (577.107 us; speedup 1.0000x reference)
//
#include <hip/hip_runtime.h>
#include <cstddef>

typedef unsigned short u16;
typedef unsigned int   u32;
typedef short  bf16x8 __attribute__((ext_vector_type(8)));
typedef float  f32x4  __attribute__((ext_vector_type(4)));

#define L_SEQ   2048
#define D_MODEL 2048
#define NHEADS  16
#define DHEAD   128
#define NBH     64
#define M_ROWS  8192
#define LOG2E   1.4426950408889634f
#define BKT     64
#define NKT     (D_MODEL / BKT)   // 32 K-tiles

__device__ __forceinline__ u16 f2bf(float f) {
  u32 u = __float_as_uint(f);
  u32 r = (u + 0x7FFFu + ((u >> 16) & 1u)) >> 16;   // RNE; inputs finite
  return (u16)r;
}
__device__ __forceinline__ float bf2f(u16 u) {
  return __uint_as_float(((u32)u) << 16);
}
__device__ __forceinline__ void load_lds16(const u16* g, u16* l) {
  __builtin_amdgcn_global_load_lds((const __attribute__((address_space(1))) u32*)g,
                                   (__attribute__((address_space(3))) u32*)l, 16, 0, 0);
}

// ======================= fused fp32 -> bf16 casts =======================
__global__ __launch_bounds__(256)
void cast_all(const float* __restrict__ x,
              const float* __restrict__ wq, const float* __restrict__ wk,
              const float* __restrict__ wv, const float* __restrict__ wo,
              u16* __restrict__ xb, u16* __restrict__ wqb, u16* __restrict__ wkb,
              u16* __restrict__ wvb, u16* __restrict__ wob) {
  const int y = blockIdx.y;
  const float* s; u16* d; int n4;
  const int NX4 = M_ROWS * D_MODEL / 4;
  const int W4  = D_MODEL * D_MODEL / 4;
  switch (y) {
    case 0: s = x;  d = xb;  n4 = NX4; break;
    case 1: s = wq; d = wqb; n4 = W4;  break;
    case 2: s = wk; d = wkb; n4 = W4;  break;
    case 3: s = wv; d = wvb; n4 = W4;  break;
    default: s = wo; d = wob; n4 = W4; break;
  }
  int i = blockIdx.x * 256 + threadIdx.x;
  if (i >= n4) return;
  float4 v = ((const float4*)s)[i];
  ushort4 o;
  o.x = f2bf(v.x); o.y = f2bf(v.y); o.z = f2bf(v.z); o.w = f2bf(v.w);
  ((ushort4*)d)[i] = o;
}

// ======================= RoPE cos/sin table: [L_SEQ][64] each =======================
__global__ __launch_bounds__(256)
void rope_table(float* __restrict__ ctab, float* __restrict__ stab) {
  const int i = blockIdx.x * 256 + threadIdx.x;   // < L_SEQ*64
  const int l = i >> 6, p = i & 63;
  const float invf = exp2f(-(float)p * (13.287712379549449f / 64.f));
  float s, c;
  sincosf((float)l * invf, &s, &c);
  ctab[i] = c;
  stab[i] = s;
}

// ======================= 256x256 tile, BK=64, 8-wave, pipelined core (r8) =======================
// One-phase-lookahead software pipeline: every MFMA cluster consumes fragments read in a PRIOR
// phase, so ds_read traffic overlaps MFMA continuously (LDS unit ~2300 cyc/K-tile/CU vs matrix
// pipes ~2048 — near-equal; overlap is the whole game at 1 block/CU).
// Steady-state iteration t (buf c = t&1; set0 = a0+b01 of tile t read at end of iter t-1):
//   P1: issue Rb23(t);            MFMA Q1 = a0 x b01          ; lgkm(0); BARRIER1
//   P2: stage A-rg0/2 <- t+2; issue Ra1(t); MFMA Q2 = a0 x b23; lgkm(0); BARRIER2
//   P3: stage B-rg0..3 <- t+2;    MFMA Q3 = a1 x b23
//   P4: stage A-rg1/3 <- t+2;     MFMA Q4 = a1 x b01
//       vmcnt(8) [retires tile t+1's 8 loads; t+2's 8 stay in flight]; BARRIER3
//       issue Ra0(t+1)+Rb01(t+1) from buf c^1
// Seals: BARRIER1's lgkm(0) covers Ra0/Rb01(t) (prev P4) + Rb23(t) -> A-rg0/2 & B stageable.
// BARRIER2's lgkm(0) covers Ra1(t) -> A-rg1/3 stageable. BARRIER3 after vmcnt(8) makes tile
// t+1's buffer block-wide visible before its set0 reads. Tail: vmcnt(0) at t==NKT-2 (only 8
// outstanding -> vmcnt(8) would pass without arrival); t==NKT-1 skips stage/vmcnt/BARRIER3/reads.
__device__ __forceinline__ void gemm256(const u16* __restrict__ Ag, const u16* __restrict__ Bg,
                                        u16* lds, f32x4 (&acc)[8][4]) {
  const int tid  = threadIdx.x;
  const int wave = tid >> 6, lane = tid & 63;
  const int quad = lane >> 4, l15 = lane & 15;
  const int wr = wave >> 2, wc = wave & 3;

#pragma unroll
  for (int m = 0; m < 8; ++m)
#pragma unroll
    for (int n = 0; n < 4; ++n) acc[m][n] = (f32x4){0.f, 0.f, 0.f, 0.f};

  const int rr  = (wave << 3) + (lane >> 3);   // 0..63
  const int ccs = (lane & 7) ^ (rr & 7);
  const u16* gA = Ag + (size_t)rr * D_MODEL + ccs * 8;
  const u16* gB = Bg + (size_t)rr * D_MODEL + ccs * 8;
  const int woff = wave * 512;

  // prologue: stage K-tiles 0 and 1 (16 loads; tile0 = oldest 8)
#pragma unroll
  for (int tt = 0; tt < 2; ++tt) {
    u16* bA = lds + tt * 32768;
    u16* bB = bA + 16384;
    const int kb = tt * BKT;
#pragma unroll
    for (int rg = 0; rg < 4; ++rg)
      load_lds16(gA + (size_t)rg * 64 * D_MODEL + kb, bA + rg * 4096 + woff);
#pragma unroll
    for (int rg = 0; rg < 4; ++rg)
      load_lds16(gB + (size_t)rg * 64 * D_MODEL + kb, bB + rg * 4096 + woff);
  }

  // loop-invariant LDS read offsets
  const int sl    = l15 & 7;
  const int slot0 = (quad ^ sl) * 8;          // kc = 0
  const int slot1 = ((4 + quad) ^ sl) * 8;    // kc = 1
  const int aOfs  = (wr * 128 + l15) * 64;
  const int bOfs  = (wc * 64 + l15) * 64;

  bf16x8 a0[4][2], a1[4][2], b01[2][2], b23[2][2];

  // pre-loop: retire tile0's 8 loads, make visible, read set0(tile0)
  asm volatile("s_waitcnt vmcnt(8)" ::: "memory");
  __builtin_amdgcn_s_barrier();
  asm volatile("" ::: "memory");
  {
    const u16* pa0 = lds + aOfs + slot0;
    const u16* pa1 = lds + aOfs + slot1;
    const u16* pb0 = lds + 16384 + bOfs + slot0;
    const u16* pb1 = lds + 16384 + bOfs + slot1;
#pragma unroll
    for (int m = 0; m < 4; ++m) {
      a0[m][0] = *(const bf16x8*)(pa0 + m * 1024);
      a0[m][1] = *(const bf16x8*)(pa1 + m * 1024);
    }
#pragma unroll
    for (int n = 0; n < 2; ++n) {
      b01[n][0] = *(const bf16x8*)(pb0 + n * 1024);
      b01[n][1] = *(const bf16x8*)(pb1 + n * 1024);
    }
  }

  for (int t = 0; t < NKT; ++t) {
    u16* bA = lds + (t & 1) * 32768;
    u16* bB = bA + 16384;
    const u16* pa0 = bA + aOfs + slot0;
    const u16* pa1 = bA + aOfs + slot1;
    const u16* pb0 = bB + bOfs + slot0;
    const u16* pb1 = bB + bOfs + slot1;
    const bool st = (t < NKT - 2);
    const int kb2 = (t + 2) * BKT;

    // ---------------- P1: issue Rb23(t); MFMA Q1 (a0 x b01) ----------------
#pragma unroll
    for (int n = 0; n < 2; ++n) {
      b23[n][0] = *(const bf16x8*)(pb0 + (n + 2) * 1024);
      b23[n][1] = *(const bf16x8*)(pb1 + (n + 2) * 1024);
    }
    __builtin_amdgcn_s_setprio(1);
#pragma unroll
    for (int m = 0; m < 4; ++m)
#pragma unroll
      for (int n = 0; n < 2; ++n)
#pragma unroll
        for (int kc = 0; kc < 2; ++kc)
          acc[m][n] = __builtin_amdgcn_mfma_f32_16x16x32_bf16(a0[m][kc], b01[n][kc], acc[m][n], 0, 0, 0);
    __builtin_amdgcn_s_setprio(0);
    asm volatile("s_waitcnt lgkmcnt(0)" ::: "memory");
    __builtin_amdgcn_s_barrier();
    asm volatile("" ::: "memory");

    // ---------------- P2: stage A-rg0/2; issue Ra1(t); MFMA Q2 (a0 x b23) ----------------
    if (st) {
      load_lds16(gA + kb2,                         bA + woff);
      load_lds16(gA + (size_t)128 * D_MODEL + kb2, bA + 8192 + woff);
    }
#pragma unroll
    for (int m = 0; m < 4; ++m) {
      a1[m][0] = *(const bf16x8*)(pa0 + (m + 4) * 1024);
      a1[m][1] = *(const bf16x8*)(pa1 + (m + 4) * 1024);
    }
    __builtin_amdgcn_s_setprio(1);
#pragma unroll
    for (int m = 0; m < 4; ++m)
#pragma unroll
      for (int n = 0; n < 2; ++n)
#pragma unroll
        for (int kc = 0; kc < 2; ++kc)
          acc[m][n + 2] = __builtin_amdgcn_mfma_f32_16x16x32_bf16(a0[m][kc], b23[n][kc], acc[m][n + 2], 0, 0, 0);
    __builtin_amdgcn_s_setprio(0);
    asm volatile("s_waitcnt lgkmcnt(0)" ::: "memory");
    __builtin_amdgcn_s_barrier();
    asm volatile("" ::: "memory");

    // ---------------- P3: stage B-rg0..3; MFMA Q3 (a1 x b23) ----------------
    if (st) {
      load_lds16(gB + kb2,                         bB + woff);
      load_lds16(gB + (size_t)64 * D_MODEL + kb2,  bB + 4096 + woff);
      load_lds16(gB + (size_t)128 * D_MODEL + kb2, bB + 8192 + woff);
      load_lds16(gB + (size_t)192 * D_MODEL + kb2, bB + 12288 + woff);
    }
    __builtin_amdgcn_s_setprio(1);
#pragma unroll
    for (int m = 0; m < 4; ++m)
#pragma unroll
      for (int n = 0; n < 2; ++n)
#pragma unroll
        for (int kc = 0; kc < 2; ++kc)
          acc[m + 4][n + 2] = __builtin_amdgcn_mfma_f32_16x16x32_bf16(a1[m][kc], b23[n][kc], acc[m + 4][n + 2], 0, 0, 0);
    __builtin_amdgcn_s_setprio(0);

    // ---------------- P4: stage A-rg1/3; MFMA Q4 (a1 x b01); vmcnt; BARRIER3; read set0(t+1) ----
    if (st) {
      load_lds16(gA + (size_t)64 * D_MODEL + kb2,  bA + 4096 + woff);
      load_lds16(gA + (size_t)192 * D_MODEL + kb2, bA + 12288 + woff);
    }
    __builtin_amdgcn_s_setprio(1);
#pragma unroll
    for (int m = 0; m < 4; ++m)
#pragma unroll
      for (int n = 0; n < 2; ++n)
#pragma unroll
        for (int kc = 0; kc < 2; ++kc)
          acc[m + 4][n] = __builtin_amdgcn_mfma_f32_16x16x32_bf16(a1[m][kc], b01[n][kc], acc[m + 4][n], 0, 0, 0);
    __builtin_amdgcn_s_setprio(0);

    if (t < NKT - 1) {
      if (t == NKT - 2) { asm volatile("s_waitcnt vmcnt(0)" ::: "memory"); }
      else              { asm volatile("s_waitcnt vmcnt(8)" ::: "memory"); }
      __builtin_amdgcn_s_barrier();
      asm volatile("" ::: "memory");
      const u16* nA = lds + ((t + 1) & 1) * 32768;
      const u16* qa0 = nA + aOfs + slot0;
      const u16* qa1 = nA + aOfs + slot1;
      const u16* qb0 = nA + 16384 + bOfs + slot0;
      const u16* qb1 = nA + 16384 + bOfs + slot1;
#pragma unroll
      for (int m = 0; m < 4; ++m) {
        a0[m][0] = *(const bf16x8*)(qa0 + m * 1024);
        a0[m][1] = *(const bf16x8*)(qa1 + m * 1024);
      }
#pragma unroll
      for (int n = 0; n < 2; ++n) {
        b01[n][0] = *(const bf16x8*)(qb0 + n * 1024);
        b01[n][1] = *(const bf16x8*)(qb1 + n * 1024);
      }
    }
  }
}

// ======================= fused QKV projection + RoPE/sigmoid, 256x256 tiles =======================
__global__ __launch_bounds__(512, 2)
void gemm_qkv256(const u16* __restrict__ A, const u16* __restrict__ W,
                 const float* __restrict__ ctab, const float* __restrict__ stab,
                 u16* __restrict__ Qo, u16* __restrict__ Ko, u16* __restrict__ Vt,
                 float* __restrict__ qsq, float* __restrict__ ksq) {
  __shared__ __align__(16) u16 lds[65536];
  const int tid  = threadIdx.x;
  const int wave = tid >> 6, lane = tid & 63;
  const int quad = lane >> 4, l15 = lane & 15;
  const int wr = wave >> 2, wc = wave & 3;
  const int rBase = blockIdx.x << 8;
  const int cBase = blockIdx.y << 8;
  const int seg = cBase >> 11;
  const int h0  = (cBase >> 7) & 15;

  f32x4 acc[8][4];
  gemm256(A + (size_t)rBase * D_MODEL, W + (size_t)cBase * D_MODEL, lds, acc);

  __syncthreads();

  const int bat = rBase >> 11;
  const int lB  = rBase & 2047;

  if (seg < 2) {
    u16* base = (seg == 0) ? Qo : Ko;
    float* sq = (seg == 0) ? qsq : ksq;
#pragma unroll
    for (int hf = 0; hf < 2; ++hf) {
      if (wr == hf) {
#pragma unroll
        for (int m = 0; m < 8; ++m)
#pragma unroll
          for (int n = 0; n < 4; ++n) {
            const int r0 = m * 16 + quad * 4;
            const int col = wc * 64 + n * 16 + l15;
#pragma unroll
            for (int r = 0; r < 4; ++r)
              lds[(r0 + r) * 264 + col] = f2bf(acc[m][n][r]);
          }
      }
      __syncthreads();
      {
        const int row = tid >> 2;
        const int q4  = tid & 3;
        const int hh = q4 >> 1, sel = q4 & 1;
        const int p0 = sel * 32;
        const int l = lB + hf * 128 + row;
        const int head = h0 + hh;
        u16* dst = base + ((size_t)(bat * NHEADS + head) * L_SEQ + l) * DHEAD;
        float ss = 0.f;
#pragma unroll
        for (int c4 = 0; c4 < 4; ++c4) {
          const bf16x8 av = *(const bf16x8*)&lds[row * 264 + hh * 128 + p0 + c4 * 8];
          const bf16x8 bv = *(const bf16x8*)&lds[row * 264 + hh * 128 + p0 + c4 * 8 + 64];
          const float4 cv1 = *(const float4*)&ctab[l * 64 + p0 + c4 * 8];
          const float4 cv2 = *(const float4*)&ctab[l * 64 + p0 + c4 * 8 + 4];
          const float4 sv1 = *(const float4*)&stab[l * 64 + p0 + c4 * 8];
          const float4 sv2 = *(const float4*)&stab[l * 64 + p0 + c4 * 8 + 4];
          const float cs[8] = {cv1.x, cv1.y, cv1.z, cv1.w, cv2.x, cv2.y, cv2.z, cv2.w};
          const float sn[8] = {sv1.x, sv1.y, sv1.z, sv1.w, sv2.x, sv2.y, sv2.z, sv2.w};
          bf16x8 out1, out2;
#pragma unroll
          for (int j = 0; j < 8; ++j) {
            const float v1 = bf2f((u16)av[j]);
            const float v2 = bf2f((u16)bv[j]);
            const float c = cs[j], s = sn[j];
            float o1 = v1 * c - v2 * s;
            float o2 = v2 * c + v1 * s;
            o1 = 1.f / (1.f + __expf(-o1));
            o2 = 1.f / (1.f + __expf(-o2));
            const u16 b1 = f2bf(o1), b2 = f2bf(o2);
            out1[j] = (short)b1; out2[j] = (short)b2;
            const float r1 = bf2f(b1), r2 = bf2f(b2);
            ss += r1 * r1 + r2 * r2;
          }
          *(bf16x8*)(dst + p0 + c4 * 8) = out1;
          *(bf16x8*)(dst + p0 + 64 + c4 * 8) = out2;
        }
        ss += __shfl_xor(ss, 1, 64);
        if (sel == 0) sq[(size_t)(bat * NHEADS + head) * L_SEQ + l] = ss;
      }
      __syncthreads();
    }
  } else {
#pragma unroll
    for (int hf = 0; hf < 2; ++hf) {
      if (wr == hf) {
#pragma unroll
        for (int m = 0; m < 8; ++m)
#pragma unroll
          for (int n = 0; n < 4; ++n) {
            const int tok = m * 16 + quad * 4;
            const int col = wc * 64 + n * 16 + l15;
            uint2 pk;
            pk.x = (u32)f2bf(acc[m][n][0]) | ((u32)f2bf(acc[m][n][1]) << 16);
            pk.y = (u32)f2bf(acc[m][n][2]) | ((u32)f2bf(acc[m][n][3]) << 16);
            *(uint2*)&lds[col * 136 + tok] = pk;
          }
      }
      __syncthreads();
      {
        const int row = tid >> 1;
        const int hk  = tid & 1;
        const int hh = row >> 7, vd = row & 127;
        u16* dst = Vt + ((size_t)(bat * NHEADS + h0 + hh) * DHEAD + vd) * L_SEQ
                 + lB + hf * 128 + hk * 64;
        const u16* src = lds + row * 136 + hk * 64;
#pragma unroll
        for (int c = 0; c < 8; ++c)
          *(bf16x8*)(dst + c * 8) = *(const bf16x8*)(src + c * 8);
      }
      __syncthreads();
    }
  }
}

// ======================= output projection: C = A * Wo^T (f32 out), 256x256 tiles ============
__global__ __launch_bounds__(512, 2)
void gemm_out256(const u16* __restrict__ A, const u16* __restrict__ W, float* __restrict__ C) {
  __shared__ __align__(16) u16 lds[65536];
  const int tid  = threadIdx.x;
  const int wave = tid >> 6, lane = tid & 63;
  const int quad = lane >> 4, l15 = lane & 15;
  const int wr = wave >> 2, wc = wave & 3;
  const int rBase = blockIdx.x << 8;
  const int cBase = blockIdx.y << 8;

  f32x4 acc[8][4];
  gemm256(A + (size_t)rBase * D_MODEL, W + (size_t)cBase * D_MODEL, lds, acc);

  const int row0 = rBase + wr * 128 + quad * 4;
  const int col0 = cBase + wc * 64 + l15;
#pragma unroll
  for (int m = 0; m < 8; ++m)
#pragma unroll
    for (int n = 0; n < 4; ++n)
#pragma unroll
      for (int r = 0; r < 4; ++r)
        C[(size_t)(row0 + m * 16 + r) * D_MODEL + col0 + n * 16] = acc[m][n][r];
}

// ======================= MFMA flash attention, BQ=256, 8 waves, dbuf K/V, counted vmcnt ==================
// (unchanged from round 4 — verified)
__device__ __forceinline__ void stage_kv(const u16* __restrict__ K, const u16* __restrict__ Vg,
                                         int bh, int kt, u16* KsD, u16* VsD, int wave, int lane) {
  const u16* Ktile = K + ((size_t)bh * L_SEQ + kt * 64) * DHEAD;
#pragma unroll
  for (int i = 0; i < 2; ++i) {
    const int s = (wave * 2 + i) * 64 + lane;
    const int n = s >> 4;
    const int c = (s & 15) ^ (n & 15);
    load_lds16(Ktile + n * DHEAD + c * 8, KsD + (size_t)(wave * 2 + i) * 512);
  }
  const u16* Vtile = Vg + (size_t)bh * DHEAD * L_SEQ + kt * 64;
#pragma unroll
  for (int i = 0; i < 2; ++i) {
    const int s = (wave * 2 + i) * 64 + lane;
    const int n = s >> 3;
    const int c = (s & 7) ^ (n & 7);
    load_lds16(Vtile + (size_t)n * L_SEQ + c * 8, VsD + (size_t)(wave * 2 + i) * 512);
  }
}

#define ATTN_TILE(KT, CUR, KH)                                                        \
  {                                                                                   \
    const int kt_ = (KT);                                                             \
    if (kt_ == nt_tiles - 1) { asm volatile("s_waitcnt vmcnt(0)" ::: "memory"); }     \
    else                     { asm volatile("s_waitcnt vmcnt(8)" ::: "memory"); }     \
    __builtin_amdgcn_s_barrier();                                                     \
    asm volatile("" ::: "memory");                                                    \
    __builtin_amdgcn_sched_barrier(0);                                                \
    if (kt_ <= 4 * qt + (wave >> 1)) {                                                \
      const bool diag = (kt_ >= 4 * qt);                                              \
      u16* Pw = &Ps[wave][0];                                                         \
      _Pragma("unroll")                                                               \
      for (int mt = 0; mt < 2; ++mt) {                                                \
        f32x4 sfr[4];                                                                 \
        _Pragma("unroll")                                                             \
        for (int nt = 0; nt < 4; ++nt) {                                              \
          f32x4 cacc = (f32x4){0.f, 0.f, 0.f, 0.f};                                   \
          const int brow = nt * 16 + l15;                                             \
          _Pragma("unroll")                                                           \
          for (int kb = 0; kb < 4; ++kb) {                                            \
            const int cc = (kb * 4 + quad) ^ l15;                                     \
            const bf16x8 bfv = *(const bf16x8*)(&Ks[CUR][brow * 128 + cc * 8]);       \
            cacc = __builtin_amdgcn_mfma_f32_16x16x32_bf16(aq[mt][kb], bfv, cacc, 0, 0, 0); \
          }                                                                           \
          sfr[nt] = cacc;                                                             \
        }                                                                             \
        const int qg0m = qBase + wave * 32 + mt * 16 + mrow;                          \
        _Pragma("unroll")                                                             \
        for (int nt = 0; nt < 4; ++nt) {                                              \
          const float kh = (KH)[nt];                                                  \
          const int kg = kt_ * 64 + nt * 16 + l15;                                    \
          _Pragma("unroll")                                                           \
          for (int r = 0; r < 4; ++r) {                                               \
            float p = exp2f(sfr[nt][r] * c2 - (qh[mt][r] + kh));                      \
            if (diag && kg > qg0m + r) p = 0.f;                                       \
            const u32 uu = __float_as_uint(p);                                        \
            lst[mt][r] += __uint_as_float(uu & 0xFFFF0000u);                          \
            Pw[(mt * 16 + mrow + r) * 72 + nt * 16 + l15] = (u16)(uu >> 16);          \
          }                                                                           \
        }                                                                             \
      }                                                                               \
      asm volatile("s_waitcnt lgkmcnt(0)" ::: "memory");                              \
      __builtin_amdgcn_sched_barrier(0);                                              \
      bf16x8 pf[2][2];                                                                \
      _Pragma("unroll")                                                               \
      for (int mt = 0; mt < 2; ++mt)                                                  \
        _Pragma("unroll")                                                             \
        for (int kb = 0; kb < 2; ++kb)                                                \
          pf[mt][kb] = *(const bf16x8*)(Pw + (mt * 16 + l15) * 72 + kb * 32 + quad * 8); \
      __builtin_amdgcn_s_setprio(1);                                                  \
      _Pragma("unroll")                                                               \
      for (int ot = 0; ot < 8; ++ot) {                                                \
        _Pragma("unroll")                                                             \
        for (int kb = 0; kb < 2; ++kb) {                                              \
          const int cc = (kb * 4 + quad) ^ (l15 & 7);                                 \
          const bf16x8 vf = *(const bf16x8*)(&Vs[CUR][(ot * 16 + l15) * 64 + cc * 8]); \
          _Pragma("unroll")                                                           \
          for (int mt = 0; mt < 2; ++mt)                                              \
            oacc[mt][ot] = __builtin_amdgcn_mfma_f32_16x16x32_bf16(pf[mt][kb], vf, oacc[mt][ot], 0, 0, 0); \
        }                                                                             \
      }                                                                               \
      __builtin_amdgcn_s_setprio(0);                                                  \
    }                                                                                 \
    asm volatile("s_waitcnt lgkmcnt(0)" ::: "memory");                                \
    __builtin_amdgcn_s_barrier();                                                     \
    asm volatile("" ::: "memory");                                                    \
    if (kt_ + 2 < nt_tiles) {                                                         \
      _Pragma("unroll")                                                               \
      for (int nt = 0; nt < 4; ++nt)                                                  \
        (KH)[nt] = ksq_g[(size_t)bh * L_SEQ + (kt_ + 2) * 64 + nt * 16 + l15] * lt;   \
      stage_kv(K, Vg, bh, kt_ + 2, &Ks[CUR][0], &Vs[CUR][0], wave, lane);             \
    }                                                                                 \
  }

__global__ __launch_bounds__(512, 2)
void attn_mfma(const u16* __restrict__ Q, const u16* __restrict__ K, const u16* __restrict__ Vg,
               const float* __restrict__ qsq_g, const float* __restrict__ ksq_g,
               const float* __restrict__ taup, u16* __restrict__ Ob) {
  __shared__ __align__(16) u16 Ks[2][64 * 128];   // [key][d], chunk c^(key&15)
  __shared__ __align__(16) u16 Vs[2][128 * 64];   // [vdim][key], chunk c^(vdim&7)
  __shared__ __align__(16) u16 Ps[8][32 * 72];    // per-wave P [q][key] bf16, pitch 72

  const int lin = (int)blockIdx.x + 8 * (int)blockIdx.y;   // grid (8, 64)
  const int idx = lin >> 3;
  const int bh  = (lin & 7) + 8 * (idx & 7);
  const int qt  = 7 - (idx >> 3);

  const int tid = threadIdx.x;
  const int wave = tid >> 6, lane = tid & 63;
  const int quad = lane >> 4, l15 = lane & 15;
  const int qBase = qt * 256;
  const int mrow = quad * 4;
  const int nt_tiles = 4 * qt + 4;   // always even, >= 4

  bf16x8 aq[2][4];
#pragma unroll
  for (int mt = 0; mt < 2; ++mt) {
    const u16* Qrow = Q + ((size_t)bh * L_SEQ + qBase + wave * 32 + mt * 16 + l15) * DHEAD;
#pragma unroll
    for (int kb = 0; kb < 4; ++kb) aq[mt][kb] = *(const bf16x8*)(Qrow + kb * 32 + quad * 8);
  }

  float tau = log1pf(expf(*taup));
  tau = fminf(fmaxf(tau, 0.1f), 10.f);
  const float lt = LOG2E / tau;
  const float c2 = 2.f * lt;

  float qh[2][4];
#pragma unroll
  for (int mt = 0; mt < 2; ++mt)
#pragma unroll
    for (int r = 0; r < 4; ++r)
      qh[mt][r] = qsq_g[(size_t)bh * L_SEQ + qBase + wave * 32 + mt * 16 + mrow + r] * lt;

  float lst[2][4] = {{0.f, 0.f, 0.f, 0.f}, {0.f, 0.f, 0.f, 0.f}};
  f32x4 oacc[2][8];
#pragma unroll
  for (int mt = 0; mt < 2; ++mt)
#pragma unroll
    for (int i = 0; i < 8; ++i) oacc[mt][i] = (f32x4){0.f, 0.f, 0.f, 0.f};

  float khA[4], khB[4];
#pragma unroll
  for (int nt = 0; nt < 4; ++nt)
    khA[nt] = ksq_g[(size_t)bh * L_SEQ + 0 * 64 + nt * 16 + l15] * lt;
  stage_kv(K, Vg, bh, 0, &Ks[0][0], &Vs[0][0], wave, lane);
#pragma unroll
  for (int nt = 0; nt < 4; ++nt)
    khB[nt] = ksq_g[(size_t)bh * L_SEQ + 1 * 64 + nt * 16 + l15] * lt;
  stage_kv(K, Vg, bh, 1, &Ks[1][0], &Vs[1][0], wave, lane);

  for (int kt2 = 0; kt2 < nt_tiles; kt2 += 2) {
    ATTN_TILE(kt2,     0, khA)
    ATTN_TILE(kt2 + 1, 1, khB)
  }

#pragma unroll
  for (int off = 1; off < 16; off <<= 1)
#pragma unroll
    for (int mt = 0; mt < 2; ++mt)
#pragma unroll
      for (int r = 0; r < 4; ++r) lst[mt][r] += __shfl_xor(lst[mt][r], off, 64);

  const int b = bh >> 4, hh = bh & 15;
#pragma unroll
  for (int mt = 0; mt < 2; ++mt)
#pragma unroll
    for (int r = 0; r < 4; ++r) {
      const float invl = 1.f / lst[mt][r];
      const int qg = qBase + wave * 32 + mt * 16 + mrow + r;
      u16* dst = Ob + ((size_t)(b * L_SEQ + qg)) * D_MODEL + hh * DHEAD;
#pragma unroll
      for (int ot = 0; ot < 8; ++ot)
        dst[ot * 16 + l15] = f2bf(oacc[mt][ot][r] * invl);
    }
}

// ======================= launch =======================
extern "C" void kernel_launch(void* const* d_in, const int* in_sizes, int n_in,
                              void* d_out, int out_size, void* d_ws, size_t ws_size,
                              hipStream_t stream) {
  const float* x     = (const float*)d_in[0];
  const float* Wq    = (const float*)d_in[1];
  const float* Wk    = (const float*)d_in[2];
  const float* Wv    = (const float*)d_in[3];
  const float* Wo    = (const float*)d_in[4];
  const float* tau_p = (const float*)d_in[5];

  const size_t NX = (size_t)M_ROWS * D_MODEL;
  const size_t NW = (size_t)D_MODEL * D_MODEL;
  u16* xb  = (u16*)d_ws;                  // aliased as Obuf after projections
  u16* Wqb = xb  + NX;
  u16* Wkb = Wqb + NW;
  u16* Wvb = Wkb + NW;
  u16* Wob = Wvb + NW;
  u16* Qb  = Wob + NW;
  u16* Kb  = Qb + NX;
  u16* Vtb = Kb + NX;                     // V^T (B,H,d,L)
  float* qsq = (float*)(Vtb + NX);
  float* ksq = qsq + (size_t)NBH * L_SEQ;
  float* ctab = ksq + (size_t)NBH * L_SEQ;     // [L_SEQ][64]
  float* stab = ctab + (size_t)L_SEQ * 64;
  u16* Obuf = xb;

  rope_table<<<dim3(L_SEQ * 64 / 256), 256, 0, stream>>>(ctab, stab);

  cast_all<<<dim3((int)(NX / 4 / 256), 5), 256, 0, stream>>>(
      x, Wq, Wk, Wv, Wo, xb, Wqb, Wkb, Wvb, Wob);

  gemm_qkv256<<<dim3(M_ROWS / 256, 24), 512, 0, stream>>>(
      xb, Wqb, ctab, stab, Qb, Kb, Vtb, qsq, ksq);

  attn_mfma<<<dim3(8, NBH), 512, 0, stream>>>(Qb, Kb, Vtb, qsq, ksq, tau_p, Obuf);

  gemm_out256<<<dim3(M_ROWS / 256, D_MODEL / 256), 512, 0, stream>>>(Obuf, Wob, (float*)d_out);
}

// Round 9
// 550.958 us; speedup vs baseline: 1.0475x; 1.0475x over previous
//
#include <hip/hip_runtime.h>
#include <cstddef>

typedef unsigned short u16;
typedef unsigned int   u32;
typedef short  bf16x8 __attribute__((ext_vector_type(8)));
typedef float  f32x4  __attribute__((ext_vector_type(4)));

#define L_SEQ   2048
#define D_MODEL 2048
#define NHEADS  16
#define DHEAD   128
#define NBH     64
#define M_ROWS  8192
#define LOG2E   1.4426950408889634f
#define BKT     64
#define NKT     (D_MODEL / BKT)   // 32 K-tiles

__device__ __forceinline__ u16 f2bf(float f) {
  u32 u = __float_as_uint(f);
  u32 r = (u + 0x7FFFu + ((u >> 16) & 1u)) >> 16;   // RNE; inputs finite
  return (u16)r;
}
__device__ __forceinline__ float bf2f(u16 u) {
  return __uint_as_float(((u32)u) << 16);
}
__device__ __forceinline__ void load_lds16(const u16* g, u16* l) {
  __builtin_amdgcn_global_load_lds((const __attribute__((address_space(1))) u32*)g,
                                   (__attribute__((address_space(3))) u32*)l, 16, 0, 0);
}

// ======================= fused fp32 -> bf16 casts =======================
__global__ __launch_bounds__(256)
void cast_all(const float* __restrict__ x,
              const float* __restrict__ wq, const float* __restrict__ wk,
              const float* __restrict__ wv, const float* __restrict__ wo,
              u16* __restrict__ xb, u16* __restrict__ wqb, u16* __restrict__ wkb,
              u16* __restrict__ wvb, u16* __restrict__ wob) {
  const int y = blockIdx.y;
  const float* s; u16* d; int n4;
  const int NX4 = M_ROWS * D_MODEL / 4;
  const int W4  = D_MODEL * D_MODEL / 4;
  switch (y) {
    case 0: s = x;  d = xb;  n4 = NX4; break;
    case 1: s = wq; d = wqb; n4 = W4;  break;
    case 2: s = wk; d = wkb; n4 = W4;  break;
    case 3: s = wv; d = wvb; n4 = W4;  break;
    default: s = wo; d = wob; n4 = W4; break;
  }
  int i = blockIdx.x * 256 + threadIdx.x;
  if (i >= n4) return;
  float4 v = ((const float4*)s)[i];
  ushort4 o;
  o.x = f2bf(v.x); o.y = f2bf(v.y); o.z = f2bf(v.z); o.w = f2bf(v.w);
  ((ushort4*)d)[i] = o;
}

// ======================= RoPE cos/sin table: [L_SEQ][64] each =======================
__global__ __launch_bounds__(256)
void rope_table(float* __restrict__ ctab, float* __restrict__ stab) {
  const int i = blockIdx.x * 256 + threadIdx.x;   // < L_SEQ*64
  const int l = i >> 6, p = i & 63;
  const float invf = exp2f(-(float)p * (13.287712379549449f / 64.f));
  float s, c;
  sincosf((float)l * invf, &s, &c);
  ctab[i] = c;
  stab[i] = s;
}

// ======================= 256x256 tile, BK=64, 8-wave, 4-phase/K-tile pipelined core =======================
// r7 core (verified 213 us on gemm_qkv): phase = {ds_reads -> staging -> MFMA -> lgkm(0) -> barrier}.
// lgkm(0) AFTER the MFMA cluster (cross-wave region seal before the phase-end barrier); compiler's
// fine-grained lgkmcnt(N) handles own-wave ds_read->MFMA deps. Hoisted LDS read bases (row&7==l15&7).
// Region handoff: A-rg0/2 last read P1, staged P2; B-rg0..2 last read P1/P2, staged P3; B-rg3 +
// A-rg1/3 last read P2/P3, staged P4. vmcnt(8) at loop top retires tile t's 8 loads; drains at tail.
__device__ __forceinline__ void gemm256(const u16* __restrict__ Ag, const u16* __restrict__ Bg,
                                        u16* lds, f32x4 (&acc)[8][4]) {
  const int tid  = threadIdx.x;
  const int wave = tid >> 6, lane = tid & 63;
  const int quad = lane >> 4, l15 = lane & 15;
  const int wr = wave >> 2, wc = wave & 3;

#pragma unroll
  for (int m = 0; m < 8; ++m)
#pragma unroll
    for (int n = 0; n < 4; ++n) acc[m][n] = (f32x4){0.f, 0.f, 0.f, 0.f};

  const int rr  = (wave << 3) + (lane >> 3);   // 0..63
  const int ccs = (lane & 7) ^ (rr & 7);
  const u16* gA = Ag + (size_t)rr * D_MODEL + ccs * 8;
  const u16* gB = Bg + (size_t)rr * D_MODEL + ccs * 8;
  const int woff = wave * 512;

  // prologue: stage K-tiles 0 and 1 (16 loads; tile0 = oldest 8)
#pragma unroll
  for (int tt = 0; tt < 2; ++tt) {
    u16* bA = lds + tt * 32768;
    u16* bB = bA + 16384;
    const int kb = tt * BKT;
#pragma unroll
    for (int rg = 0; rg < 4; ++rg)
      load_lds16(gA + (size_t)rg * 64 * D_MODEL + kb, bA + rg * 4096 + woff);
#pragma unroll
    for (int rg = 0; rg < 4; ++rg)
      load_lds16(gB + (size_t)rg * 64 * D_MODEL + kb, bB + rg * 4096 + woff);
  }

  // loop-invariant LDS read bases
  const int sl    = l15 & 7;
  const int slot0 = (quad ^ sl) * 8;          // kc = 0
  const int slot1 = ((4 + quad) ^ sl) * 8;    // kc = 1
  const int aOfs  = (wr * 128 + l15) * 64;
  const int bOfs  = (wc * 64 + l15) * 64;

  bf16x8 a0[4][2], a1[4][2], b01[2][2], b23[2][2];

  for (int t = 0; t < NKT; ++t) {
    if (t == NKT - 1) { asm volatile("s_waitcnt vmcnt(0)" ::: "memory"); }
    else              { asm volatile("s_waitcnt vmcnt(8)" ::: "memory"); }
    __builtin_amdgcn_s_barrier();
    asm volatile("" ::: "memory");

    u16* bA = lds + (t & 1) * 32768;
    u16* bB = bA + 16384;
    const u16* pa0 = bA + aOfs + slot0;
    const u16* pa1 = bA + aOfs + slot1;
    const u16* pb0 = bB + bOfs + slot0;
    const u16* pb1 = bB + bOfs + slot1;
    const bool st = (t < NKT - 2);
    const int kb2 = (t + 2) * BKT;

    // ---------------- P1: read a0 (m0-3) + b01; MFMA (m0-3, n01) ----------------
#pragma unroll
    for (int m = 0; m < 4; ++m) {
      a0[m][0] = *(const bf16x8*)(pa0 + m * 1024);
      a0[m][1] = *(const bf16x8*)(pa1 + m * 1024);
    }
#pragma unroll
    for (int n = 0; n < 2; ++n) {
      b01[n][0] = *(const bf16x8*)(pb0 + n * 1024);
      b01[n][1] = *(const bf16x8*)(pb1 + n * 1024);
    }
    __builtin_amdgcn_s_setprio(1);
#pragma unroll
    for (int m = 0; m < 4; ++m)
#pragma unroll
      for (int n = 0; n < 2; ++n)
#pragma unroll
        for (int kc = 0; kc < 2; ++kc)
          acc[m][n] = __builtin_amdgcn_mfma_f32_16x16x32_bf16(a0[m][kc], b01[n][kc], acc[m][n], 0, 0, 0);
    __builtin_amdgcn_s_setprio(0);
    asm volatile("s_waitcnt lgkmcnt(0)" ::: "memory");
    __builtin_amdgcn_s_barrier();
    asm volatile("" ::: "memory");

    // ---------------- P2: read b23; stage A rg0,rg2; MFMA (m0-3, n23) ----------------
#pragma unroll
    for (int n = 0; n < 2; ++n) {
      b23[n][0] = *(const bf16x8*)(pb0 + (n + 2) * 1024);
      b23[n][1] = *(const bf16x8*)(pb1 + (n + 2) * 1024);
    }
    if (st) {
      load_lds16(gA + kb2,                         bA + woff);
      load_lds16(gA + (size_t)128 * D_MODEL + kb2, bA + 8192 + woff);
    }
    __builtin_amdgcn_s_setprio(1);
#pragma unroll
    for (int m = 0; m < 4; ++m)
#pragma unroll
      for (int n = 0; n < 2; ++n)
#pragma unroll
        for (int kc = 0; kc < 2; ++kc)
          acc[m][n + 2] = __builtin_amdgcn_mfma_f32_16x16x32_bf16(a0[m][kc], b23[n][kc], acc[m][n + 2], 0, 0, 0);
    __builtin_amdgcn_s_setprio(0);
    asm volatile("s_waitcnt lgkmcnt(0)" ::: "memory");
    __builtin_amdgcn_s_barrier();
    asm volatile("" ::: "memory");

    // ---------------- P3: read a1 (m4-7); stage B rg0,rg1,rg2; MFMA (m4-7, n23) ----------------
#pragma unroll
    for (int m = 0; m < 4; ++m) {
      a1[m][0] = *(const bf16x8*)(pa0 + (m + 4) * 1024);
      a1[m][1] = *(const bf16x8*)(pa1 + (m + 4) * 1024);
    }
    if (st) {
      load_lds16(gB + kb2,                         bB + woff);
      load_lds16(gB + (size_t)64 * D_MODEL + kb2,  bB + 4096 + woff);
      load_lds16(gB + (size_t)128 * D_MODEL + kb2, bB + 8192 + woff);
    }
    __builtin_amdgcn_s_setprio(1);
#pragma unroll
    for (int m = 0; m < 4; ++m)
#pragma unroll
      for (int n = 0; n < 2; ++n)
#pragma unroll
        for (int kc = 0; kc < 2; ++kc)
          acc[m + 4][n + 2] = __builtin_amdgcn_mfma_f32_16x16x32_bf16(a1[m][kc], b23[n][kc], acc[m + 4][n + 2], 0, 0, 0);
    __builtin_amdgcn_s_setprio(0);
    asm volatile("s_waitcnt lgkmcnt(0)" ::: "memory");
    __builtin_amdgcn_s_barrier();
    asm volatile("" ::: "memory");

    // ---------------- P4: stage B rg3 + A rg1,rg3; MFMA (m4-7, n01) ----------------
    if (st) {
      load_lds16(gB + (size_t)192 * D_MODEL + kb2, bB + 12288 + woff);
      load_lds16(gA + (size_t)64 * D_MODEL + kb2,  bA + 4096 + woff);
      load_lds16(gA + (size_t)192 * D_MODEL + kb2, bA + 12288 + woff);
    }
    __builtin_amdgcn_s_setprio(1);
#pragma unroll
    for (int m = 0; m < 4; ++m)
#pragma unroll
      for (int n = 0; n < 2; ++n)
#pragma unroll
        for (int kc = 0; kc < 2; ++kc)
          acc[m + 4][n] = __builtin_amdgcn_mfma_f32_16x16x32_bf16(a1[m][kc], b01[n][kc], acc[m + 4][n], 0, 0, 0);
    __builtin_amdgcn_s_setprio(0);
    // P4 issues no ds_reads; loop-top vmcnt + barrier closes the K-tile
  }
}

// ======================= fused QKV projection + RoPE/sigmoid, 256x256 tiles =======================
__global__ __launch_bounds__(512, 2)
void gemm_qkv256(const u16* __restrict__ A, const u16* __restrict__ W,
                 const float* __restrict__ ctab, const float* __restrict__ stab,
                 u16* __restrict__ Qo, u16* __restrict__ Ko, u16* __restrict__ Vt,
                 float* __restrict__ qsq, float* __restrict__ ksq) {
  __shared__ __align__(16) u16 lds[65536];
  const int tid  = threadIdx.x;
  const int wave = tid >> 6, lane = tid & 63;
  const int quad = lane >> 4, l15 = lane & 15;
  const int wr = wave >> 2, wc = wave & 3;
  const int rBase = blockIdx.x << 8;
  const int cBase = blockIdx.y << 8;
  const int seg = cBase >> 11;
  const int h0  = (cBase >> 7) & 15;

  f32x4 acc[8][4];
  gemm256(A + (size_t)rBase * D_MODEL, W + (size_t)cBase * D_MODEL, lds, acc);

  __syncthreads();

  const int bat = rBase >> 11;
  const int lB  = rBase & 2047;

  if (seg < 2) {
    u16* base = (seg == 0) ? Qo : Ko;
    float* sq = (seg == 0) ? qsq : ksq;
#pragma unroll
    for (int hf = 0; hf < 2; ++hf) {
      if (wr == hf) {
#pragma unroll
        for (int m = 0; m < 8; ++m)
#pragma unroll
          for (int n = 0; n < 4; ++n) {
            const int r0 = m * 16 + quad * 4;
            const int col = wc * 64 + n * 16 + l15;
#pragma unroll
            for (int r = 0; r < 4; ++r)
              lds[(r0 + r) * 264 + col] = f2bf(acc[m][n][r]);
          }
      }
      __syncthreads();
      {
        const int row = tid >> 2;
        const int q4  = tid & 3;
        const int hh = q4 >> 1, sel = q4 & 1;
        const int p0 = sel * 32;
        const int l = lB + hf * 128 + row;
        const int head = h0 + hh;
        u16* dst = base + ((size_t)(bat * NHEADS + head) * L_SEQ + l) * DHEAD;
        float ss = 0.f;
#pragma unroll
        for (int c4 = 0; c4 < 4; ++c4) {
          const bf16x8 av = *(const bf16x8*)&lds[row * 264 + hh * 128 + p0 + c4 * 8];
          const bf16x8 bv = *(const bf16x8*)&lds[row * 264 + hh * 128 + p0 + c4 * 8 + 64];
          const float4 cv1 = *(const float4*)&ctab[l * 64 + p0 + c4 * 8];
          const float4 cv2 = *(const float4*)&ctab[l * 64 + p0 + c4 * 8 + 4];
          const float4 sv1 = *(const float4*)&stab[l * 64 + p0 + c4 * 8];
          const float4 sv2 = *(const float4*)&stab[l * 64 + p0 + c4 * 8 + 4];
          const float cs[8] = {cv1.x, cv1.y, cv1.z, cv1.w, cv2.x, cv2.y, cv2.z, cv2.w};
          const float sn[8] = {sv1.x, sv1.y, sv1.z, sv1.w, sv2.x, sv2.y, sv2.z, sv2.w};
          bf16x8 out1, out2;
#pragma unroll
          for (int j = 0; j < 8; ++j) {
            const float v1 = bf2f((u16)av[j]);
            const float v2 = bf2f((u16)bv[j]);
            const float c = cs[j], s = sn[j];
            float o1 = v1 * c - v2 * s;
            float o2 = v2 * c + v1 * s;
            o1 = 1.f / (1.f + __expf(-o1));
            o2 = 1.f / (1.f + __expf(-o2));
            const u16 b1 = f2bf(o1), b2 = f2bf(o2);
            out1[j] = (short)b1; out2[j] = (short)b2;
            const float r1 = bf2f(b1), r2 = bf2f(b2);
            ss += r1 * r1 + r2 * r2;
          }
          *(bf16x8*)(dst + p0 + c4 * 8) = out1;
          *(bf16x8*)(dst + p0 + 64 + c4 * 8) = out2;
        }
        ss += __shfl_xor(ss, 1, 64);
        if (sel == 0) sq[(size_t)(bat * NHEADS + head) * L_SEQ + l] = ss;
      }
      __syncthreads();
    }
  } else {
#pragma unroll
    for (int hf = 0; hf < 2; ++hf) {
      if (wr == hf) {
#pragma unroll
        for (int m = 0; m < 8; ++m)
#pragma unroll
          for (int n = 0; n < 4; ++n) {
            const int tok = m * 16 + quad * 4;
            const int col = wc * 64 + n * 16 + l15;
            uint2 pk;
            pk.x = (u32)f2bf(acc[m][n][0]) | ((u32)f2bf(acc[m][n][1]) << 16);
            pk.y = (u32)f2bf(acc[m][n][2]) | ((u32)f2bf(acc[m][n][3]) << 16);
            *(uint2*)&lds[col * 136 + tok] = pk;
          }
      }
      __syncthreads();
      {
        const int row = tid >> 1;
        const int hk  = tid & 1;
        const int hh = row >> 7, vd = row & 127;
        u16* dst = Vt + ((size_t)(bat * NHEADS + h0 + hh) * DHEAD + vd) * L_SEQ
                 + lB + hf * 128 + hk * 64;
        const u16* src = lds + row * 136 + hk * 64;
#pragma unroll
        for (int c = 0; c < 8; ++c)
          *(bf16x8*)(dst + c * 8) = *(const bf16x8*)(src + c * 8);
      }
      __syncthreads();
    }
  }
}

// ======================= output projection: C = A * Wo^T (f32 out), 256x256 tiles ============
__global__ __launch_bounds__(512, 2)
void gemm_out256(const u16* __restrict__ A, const u16* __restrict__ W, float* __restrict__ C) {
  __shared__ __align__(16) u16 lds[65536];
  const int tid  = threadIdx.x;
  const int wave = tid >> 6, lane = tid & 63;
  const int quad = lane >> 4, l15 = lane & 15;
  const int wr = wave >> 2, wc = wave & 3;
  const int rBase = blockIdx.x << 8;
  const int cBase = blockIdx.y << 8;

  f32x4 acc[8][4];
  gemm256(A + (size_t)rBase * D_MODEL, W + (size_t)cBase * D_MODEL, lds, acc);

  const int row0 = rBase + wr * 128 + quad * 4;
  const int col0 = cBase + wc * 64 + l15;
#pragma unroll
  for (int m = 0; m < 8; ++m)
#pragma unroll
    for (int n = 0; n < 4; ++n)
#pragma unroll
      for (int r = 0; r < 4; ++r)
        C[(size_t)(row0 + m * 16 + r) * D_MODEL + col0 + n * 16] = acc[m][n][r];
}

// ======================= MFMA flash attention, BQ=256, 8 waves, dbuf K/V, counted vmcnt ==================
// r9: sched_barrier(0) pins removed (loop-top + post-softmax). The post-softmax lgkmcnt(0) STAYS:
// P goes through LDS cross-lane (lane reads P-row l15 written by lane quad=l15>>2) — compiler
// dependency tracking cannot see cross-lane deps, the explicit wave-level drain is load-bearing.
// The post-PV lgkm(0)+barrier (cross-wave seal before stage_kv overwrites Ks/Vs[CUR]) also stays.
__device__ __forceinline__ void stage_kv(const u16* __restrict__ K, const u16* __restrict__ Vg,
                                         int bh, int kt, u16* KsD, u16* VsD, int wave, int lane) {
  const u16* Ktile = K + ((size_t)bh * L_SEQ + kt * 64) * DHEAD;
#pragma unroll
  for (int i = 0; i < 2; ++i) {
    const int s = (wave * 2 + i) * 64 + lane;
    const int n = s >> 4;
    const int c = (s & 15) ^ (n & 15);
    load_lds16(Ktile + n * DHEAD + c * 8, KsD + (size_t)(wave * 2 + i) * 512);
  }
  const u16* Vtile = Vg + (size_t)bh * DHEAD * L_SEQ + kt * 64;
#pragma unroll
  for (int i = 0; i < 2; ++i) {
    const int s = (wave * 2 + i) * 64 + lane;
    const int n = s >> 3;
    const int c = (s & 7) ^ (n & 7);
    load_lds16(Vtile + (size_t)n * L_SEQ + c * 8, VsD + (size_t)(wave * 2 + i) * 512);
  }
}

#define ATTN_TILE(KT, CUR, KH)                                                        \
  {                                                                                   \
    const int kt_ = (KT);                                                             \
    if (kt_ == nt_tiles - 1) { asm volatile("s_waitcnt vmcnt(0)" ::: "memory"); }     \
    else                     { asm volatile("s_waitcnt vmcnt(8)" ::: "memory"); }     \
    __builtin_amdgcn_s_barrier();                                                     \
    asm volatile("" ::: "memory");                                                    \
    if (kt_ <= 4 * qt + (wave >> 1)) {                                                \
      const bool diag = (kt_ >= 4 * qt);                                              \
      u16* Pw = &Ps[wave][0];                                                         \
      _Pragma("unroll")                                                               \
      for (int mt = 0; mt < 2; ++mt) {                                                \
        f32x4 sfr[4];                                                                 \
        _Pragma("unroll")                                                             \
        for (int nt = 0; nt < 4; ++nt) {                                              \
          f32x4 cacc = (f32x4){0.f, 0.f, 0.f, 0.f};                                   \
          const int brow = nt * 16 + l15;                                             \
          _Pragma("unroll")                                                           \
          for (int kb = 0; kb < 4; ++kb) {                                            \
            const int cc = (kb * 4 + quad) ^ l15;                                     \
            const bf16x8 bfv = *(const bf16x8*)(&Ks[CUR][brow * 128 + cc * 8]);       \
            cacc = __builtin_amdgcn_mfma_f32_16x16x32_bf16(aq[mt][kb], bfv, cacc, 0, 0, 0); \
          }                                                                           \
          sfr[nt] = cacc;                                                             \
        }                                                                             \
        const int qg0m = qBase + wave * 32 + mt * 16 + mrow;                          \
        _Pragma("unroll")                                                             \
        for (int nt = 0; nt < 4; ++nt) {                                              \
          const float kh = (KH)[nt];                                                  \
          const int kg = kt_ * 64 + nt * 16 + l15;                                    \
          _Pragma("unroll")                                                           \
          for (int r = 0; r < 4; ++r) {                                               \
            float p = exp2f(sfr[nt][r] * c2 - (qh[mt][r] + kh));                      \
            if (diag && kg > qg0m + r) p = 0.f;                                       \
            const u32 uu = __float_as_uint(p);                                        \
            lst[mt][r] += __uint_as_float(uu & 0xFFFF0000u);                          \
            Pw[(mt * 16 + mrow + r) * 72 + nt * 16 + l15] = (u16)(uu >> 16);          \
          }                                                                           \
        }                                                                             \
      }                                                                               \
      asm volatile("s_waitcnt lgkmcnt(0)" ::: "memory");                              \
      bf16x8 pf[2][2];                                                                \
      _Pragma("unroll")                                                               \
      for (int mt = 0; mt < 2; ++mt)                                                  \
        _Pragma("unroll")                                                             \
        for (int kb = 0; kb < 2; ++kb)                                                \
          pf[mt][kb] = *(const bf16x8*)(Pw + (mt * 16 + l15) * 72 + kb * 32 + quad * 8); \
      __builtin_amdgcn_s_setprio(1);                                                  \
      _Pragma("unroll")                                                               \
      for (int ot = 0; ot < 8; ++ot) {                                                \
        _Pragma("unroll")                                                             \
        for (int kb = 0; kb < 2; ++kb) {                                              \
          const int cc = (kb * 4 + quad) ^ (l15 & 7);                                 \
          const bf16x8 vf = *(const bf16x8*)(&Vs[CUR][(ot * 16 + l15) * 64 + cc * 8]); \
          _Pragma("unroll")                                                           \
          for (int mt = 0; mt < 2; ++mt)                                              \
            oacc[mt][ot] = __builtin_amdgcn_mfma_f32_16x16x32_bf16(pf[mt][kb], vf, oacc[mt][ot], 0, 0, 0); \
        }                                                                             \
      }                                                                               \
      __builtin_amdgcn_s_setprio(0);                                                  \
    }                                                                                 \
    asm volatile("s_waitcnt lgkmcnt(0)" ::: "memory");                                \
    __builtin_amdgcn_s_barrier();                                                     \
    asm volatile("" ::: "memory");                                                    \
    if (kt_ + 2 < nt_tiles) {                                                         \
      _Pragma("unroll")                                                               \
      for (int nt = 0; nt < 4; ++nt)                                                  \
        (KH)[nt] = ksq_g[(size_t)bh * L_SEQ + (kt_ + 2) * 64 + nt * 16 + l15] * lt;   \
      stage_kv(K, Vg, bh, kt_ + 2, &Ks[CUR][0], &Vs[CUR][0], wave, lane);             \
    }                                                                                 \
  }

__global__ __launch_bounds__(512, 2)
void attn_mfma(const u16* __restrict__ Q, const u16* __restrict__ K, const u16* __restrict__ Vg,
               const float* __restrict__ qsq_g, const float* __restrict__ ksq_g,
               const float* __restrict__ taup, u16* __restrict__ Ob) {
  __shared__ __align__(16) u16 Ks[2][64 * 128];   // [key][d], chunk c^(key&15)
  __shared__ __align__(16) u16 Vs[2][128 * 64];   // [vdim][key], chunk c^(vdim&7)
  __shared__ __align__(16) u16 Ps[8][32 * 72];    // per-wave P [q][key] bf16, pitch 72

  const int lin = (int)blockIdx.x + 8 * (int)blockIdx.y;   // grid (8, 64)
  const int idx = lin >> 3;
  const int bh  = (lin & 7) + 8 * (idx & 7);
  const int qt  = 7 - (idx >> 3);

  const int tid = threadIdx.x;
  const int wave = tid >> 6, lane = tid & 63;
  const int quad = lane >> 4, l15 = lane & 15;
  const int qBase = qt * 256;
  const int mrow = quad * 4;
  const int nt_tiles = 4 * qt + 4;   // always even, >= 4

  bf16x8 aq[2][4];
#pragma unroll
  for (int mt = 0; mt < 2; ++mt) {
    const u16* Qrow = Q + ((size_t)bh * L_SEQ + qBase + wave * 32 + mt * 16 + l15) * DHEAD;
#pragma unroll
    for (int kb = 0; kb < 4; ++kb) aq[mt][kb] = *(const bf16x8*)(Qrow + kb * 32 + quad * 8);
  }

  float tau = log1pf(expf(*taup));
  tau = fminf(fmaxf(tau, 0.1f), 10.f);
  const float lt = LOG2E / tau;
  const float c2 = 2.f * lt;

  float qh[2][4];
#pragma unroll
  for (int mt = 0; mt < 2; ++mt)
#pragma unroll
    for (int r = 0; r < 4; ++r)
      qh[mt][r] = qsq_g[(size_t)bh * L_SEQ + qBase + wave * 32 + mt * 16 + mrow + r] * lt;

  float lst[2][4] = {{0.f, 0.f, 0.f, 0.f}, {0.f, 0.f, 0.f, 0.f}};
  f32x4 oacc[2][8];
#pragma unroll
  for (int mt = 0; mt < 2; ++mt)
#pragma unroll
    for (int i = 0; i < 8; ++i) oacc[mt][i] = (f32x4){0.f, 0.f, 0.f, 0.f};

  float khA[4], khB[4];
#pragma unroll
  for (int nt = 0; nt < 4; ++nt)
    khA[nt] = ksq_g[(size_t)bh * L_SEQ + 0 * 64 + nt * 16 + l15] * lt;
  stage_kv(K, Vg, bh, 0, &Ks[0][0], &Vs[0][0], wave, lane);
#pragma unroll
  for (int nt = 0; nt < 4; ++nt)
    khB[nt] = ksq_g[(size_t)bh * L_SEQ + 1 * 64 + nt * 16 + l15] * lt;
  stage_kv(K, Vg, bh, 1, &Ks[1][0], &Vs[1][0], wave, lane);

  for (int kt2 = 0; kt2 < nt_tiles; kt2 += 2) {
    ATTN_TILE(kt2,     0, khA)
    ATTN_TILE(kt2 + 1, 1, khB)
  }

#pragma unroll
  for (int off = 1; off < 16; off <<= 1)
#pragma unroll
    for (int mt = 0; mt < 2; ++mt)
#pragma unroll
      for (int r = 0; r < 4; ++r) lst[mt][r] += __shfl_xor(lst[mt][r], off, 64);

  const int b = bh >> 4, hh = bh & 15;
#pragma unroll
  for (int mt = 0; mt < 2; ++mt)
#pragma unroll
    for (int r = 0; r < 4; ++r) {
      const float invl = 1.f / lst[mt][r];
      const int qg = qBase + wave * 32 + mt * 16 + mrow + r;
      u16* dst = Ob + ((size_t)(b * L_SEQ + qg)) * D_MODEL + hh * DHEAD;
#pragma unroll
      for (int ot = 0; ot < 8; ++ot)
        dst[ot * 16 + l15] = f2bf(oacc[mt][ot][r] * invl);
    }
}

// ======================= launch =======================
extern "C" void kernel_launch(void* const* d_in, const int* in_sizes, int n_in,
                              void* d_out, int out_size, void* d_ws, size_t ws_size,
                              hipStream_t stream) {
  const float* x     = (const float*)d_in[0];
  const float* Wq    = (const float*)d_in[1];
  const float* Wk    = (const float*)d_in[2];
  const float* Wv    = (const float*)d_in[3];
  const float* Wo    = (const float*)d_in[4];
  const float* tau_p = (const float*)d_in[5];

  const size_t NX = (size_t)M_ROWS * D_MODEL;
  const size_t NW = (size_t)D_MODEL * D_MODEL;
  u16* xb  = (u16*)d_ws;                  // aliased as Obuf after projections
  u16* Wqb = xb  + NX;
  u16* Wkb = Wqb + NW;
  u16* Wvb = Wkb + NW;
  u16* Wob = Wvb + NW;
  u16* Qb  = Wob + NW;
  u16* Kb  = Qb + NX;
  u16* Vtb = Kb + NX;                     // V^T (B,H,d,L)
  float* qsq = (float*)(Vtb + NX);
  float* ksq = qsq + (size_t)NBH * L_SEQ;
  float* ctab = ksq + (size_t)NBH * L_SEQ;     // [L_SEQ][64]
  float* stab = ctab + (size_t)L_SEQ * 64;
  u16* Obuf = xb;

  rope_table<<<dim3(L_SEQ * 64 / 256), 256, 0, stream>>>(ctab, stab);

  cast_all<<<dim3((int)(NX / 4 / 256), 5), 256, 0, stream>>>(
      x, Wq, Wk, Wv, Wo, xb, Wqb, Wkb, Wvb, Wob);

  gemm_qkv256<<<dim3(M_ROWS / 256, 24), 512, 0, stream>>>(
      xb, Wqb, ctab, stab, Qb, Kb, Vtb, qsq, ksq);

  attn_mfma<<<dim3(8, NBH), 512, 0, stream>>>(Qb, Kb, Vtb, qsq, ksq, tau_p, Obuf);

  gemm_out256<<<dim3(M_ROWS / 256, D_MODEL / 256), 512, 0, stream>>>(Obuf, Wob, (float*)d_out);
}